// Round 4
// baseline (887.186 us; speedup 1.0000x reference)
//
#include <hip/hip_runtime.h>

#define NROWS    262144   // 16 * 16384
#define DIMS     64
#define KCODES   512
#define MTILE    64       // rows per block: 8 row-groups x 8 rows
#define CHUNK    256      // cols per LDS chunk
#define NCHUNK   2
#define NTHREADS 1024     // 16 waves = 8 wave-pairs

// ---------------------------------------------------------------------------
// prep: embedT[k][d] = embed[d][k]; enorm[k] = sum_d embed[d][k]^2 (numpy
// pairwise-8 order); zero the likelihood accumulator.
// ---------------------------------------------------------------------------
__global__ void prep_kernel(const float* __restrict__ embed,
                            float* __restrict__ embedT,
                            float* __restrict__ enorm,
                            float* __restrict__ lik) {
    int k = blockIdx.x;
    int d = threadIdx.x;
    float v = embed[d * KCODES + k];
    embedT[k * DIMS + d] = v;
    float sq = __fmul_rn(v, v);
    int j = d & 7;
    float r = __shfl(sq, j, 64);
#pragma unroll
    for (int i = 1; i < 8; ++i)
        r = __fadd_rn(r, __shfl(sq, j + 8 * i, 64));
    float t;
    t = __shfl_xor(r, 1, 64); r = __fadd_rn(r, t);
    t = __shfl_xor(r, 2, 64); r = __fadd_rn(r, t);
    t = __shfl_xor(r, 4, 64); r = __fadd_rn(r, t);
    if (d == 0) { enorm[k] = r; lik[k] = 0.0f; }
}

// ---------------------------------------------------------------------------
// main: block = 64 rows x 512 cols, 1024 threads (16 waves = 8 pairs).
// Wave w: rgrp = w&7 -> rows [rgrp*8, +8); half = w>>3 -> col-half of each
// 256-col chunk. Lane owns 2 adjacent cols per chunk -> acc[2][8][2] = 32
// VGPRs. DESIGN POINT: the backend allocator insists on a 64-VGPR budget
// (8 waves/EU); rounds 1-3 spilled 36 floats/thread (288 MiB scratch
// traffic, WRITE_SIZE 352 MiB). This layout fits the 64 budget AND makes
// 8 waves/EU real (1024 thr x 64 KB LDS -> 2 blocks/CU = 32 waves/CU).
// Softmax: in-wave reduce over 256 cols + pair exchange (w ^ 8) via LDS.
// z per element keeps the exact round-1 FMA chain -> argmax bit-exact.
// ---------------------------------------------------------------------------
__global__ void __launch_bounds__(NTHREADS)
main_kernel(const float* __restrict__ x,
            const float* __restrict__ embed,
            const float* __restrict__ sigma,
            const float* __restrict__ embedT,
            const float* __restrict__ enorm,
            float* __restrict__ lik,
            float* __restrict__ out) {
    __shared__ float e_lds[DIMS * CHUNK];   // 64 KB

    const int tid  = threadIdx.x;
    const int lane = tid & 63;
    const int w    = tid >> 6;          // wave id 0..15
    const int rgrp = w & 7;
    const int half = w >> 3;            // col half 0/1
    const int rowbase = blockIdx.x * MTILE + rgrp * 8;
    const int colb = half * 128 + 2 * lane;   // within-chunk col base (2 cols)

    const float sigma_v = sigma[0];

    float acc[NCHUNK][8][2];
#pragma unroll
    for (int c = 0; c < NCHUNK; ++c)
#pragma unroll
        for (int r = 0; r < 8; ++r) { acc[c][r][0] = 0.0f; acc[c][r][1] = 0.0f; }

    const float4* __restrict__ x4  = reinterpret_cast<const float4*>(x);
    const float4* __restrict__ eg4 = reinterpret_cast<const float4*>(embed);

#pragma unroll
    for (int ch = 0; ch < NCHUNK; ++ch) {
        __syncthreads();
        // stage chunk: 4096 float4 / 1024 threads = 4 each
#pragma unroll
        for (int i = 0; i < 4; ++i) {
            int f4 = tid + i * NTHREADS;
            int d  = f4 >> 6;
            int c4 = f4 & 63;
            reinterpret_cast<float4*>(e_lds)[d * 64 + c4] =
                eg4[d * 128 + ch * 64 + c4];
        }
        __syncthreads();

        const float2* e2 = reinterpret_cast<const float2*>(e_lds);
        const int cb2 = half * 64 + lane;   // float2 index within a d-row
#pragma unroll 2
        for (int d = 0; d < DIMS; d += 4) {
            float2 ea = e2[(d + 0) * 128 + cb2];
            float2 eb = e2[(d + 1) * 128 + cb2];
            float2 ec = e2[(d + 2) * 128 + cb2];
            float2 ed = e2[(d + 3) * 128 + cb2];
            int d4 = d >> 2;
#pragma unroll
            for (int r = 0; r < 8; ++r) {
                float4 xv = x4[(rowbase + r) * 16 + d4];
                // ascending-d sequential fma chain per (r,col) — bit-exact
                acc[ch][r][0] = fmaf(xv.x, ea.x, acc[ch][r][0]);
                acc[ch][r][1] = fmaf(xv.x, ea.y, acc[ch][r][1]);
                acc[ch][r][0] = fmaf(xv.y, eb.x, acc[ch][r][0]);
                acc[ch][r][1] = fmaf(xv.y, eb.y, acc[ch][r][1]);
                acc[ch][r][0] = fmaf(xv.z, ec.x, acc[ch][r][0]);
                acc[ch][r][1] = fmaf(xv.z, ec.y, acc[ch][r][1]);
                acc[ch][r][0] = fmaf(xv.w, ed.x, acc[ch][r][0]);
                acc[ch][r][1] = fmaf(xv.w, ed.y, acc[ch][r][1]);
            }
        }
    }

    __syncthreads();   // e_lds reads done; reuse as exchange buffer

    // ---- xnorm for the wave's 8 rows (numpy pairwise-8 order) ----
    const int r_l = lane >> 3;
    const int j_l = lane & 7;
    float xr;
    {
        const float* xp = x + (size_t)(rowbase + r_l) * DIMS + j_l;
        float v0 = xp[0];
        float s = __fmul_rn(v0, v0);
#pragma unroll
        for (int i = 1; i < 8; ++i) {
            float v = xp[8 * i];
            s = __fadd_rn(s, __fmul_rn(v, v));
        }
        float t;
        t = __shfl_xor(s, 1, 64); s = __fadd_rn(s, t);
        t = __shfl_xor(s, 2, 64); s = __fadd_rn(s, t);
        t = __shfl_xor(s, 4, 64); s = __fadd_rn(s, t);
        xr = s;   // lane r*8+j holds xnorm of row r
    }

    float en[NCHUNK][2];
#pragma unroll
    for (int c = 0; c < NCHUNK; ++c) {
        en[c][0] = enorm[c * CHUNK + colb + 0];
        en[c][1] = enorm[c * CHUNK + colb + 1];
    }

    float likpart[NCHUNK][2];
#pragma unroll
    for (int c = 0; c < NCHUNK; ++c) { likpart[c][0] = 0.0f; likpart[c][1] = 0.0f; }

    const int pw = w ^ 8;   // pair partner wave

    // two groups of 4 rows; each group: [z,m] exchange, [ee,s,best] exchange
#pragma unroll
    for (int g = 0; g < 2; ++g) {
        const int base = g * 512;   // ping-pong region in e_lds
        float mw[4];
#pragma unroll
        for (int i = 0; i < 4; ++i) {
            int r = g * 4 + i;
            float xn = __shfl(xr, r * 8, 64);
            float mm = -INFINITY;
#pragma unroll
            for (int c = 0; c < NCHUNK; ++c)
#pragma unroll
                for (int q = 0; q < 2; ++q) {
                    float dot  = acc[c][r][q];
                    float td   = __fsub_rn(xn, __fmul_rn(2.0f, dot));
                    float dist = __fadd_rn(td, en[c][q]);
                    float zz   = __fmul_rn(-sigma_v, dist);
                    acc[c][r][q] = zz;
                    mm = fmaxf(mm, zz);
                }
#pragma unroll
            for (int mask = 1; mask < 64; mask <<= 1)
                mm = fmaxf(mm, __shfl_xor(mm, mask, 64));
            mw[i] = mm;
        }
        if (lane < 4) e_lds[base + w * 4 + lane] = mw[lane];
        __syncthreads();
#pragma unroll
        for (int i = 0; i < 4; ++i)
            mw[i] = fmaxf(mw[i], e_lds[base + pw * 4 + i]);

        float sw[4], bv[4]; int bc[4];
#pragma unroll
        for (int i = 0; i < 4; ++i) {
            int r = g * 4 + i;
            float ssum = 0.0f, best = -1.0f; int bcol = KCODES;
#pragma unroll
            for (int c = 0; c < NCHUNK; ++c)
#pragma unroll
                for (int q = 0; q < 2; ++q) {
                    float ee = expf(__fsub_rn(acc[c][r][q], mw[i]));
                    acc[c][r][q] = ee;
                    ssum += ee;
                    int col = c * CHUNK + colb + q;
                    if (ee > best) { best = ee; bcol = col; }
                }
#pragma unroll
            for (int mask = 1; mask < 64; mask <<= 1)
                ssum += __shfl_xor(ssum, mask, 64);
#pragma unroll
            for (int mask = 1; mask < 64; mask <<= 1) {
                float ov = __shfl_xor(best, mask, 64);
                int   oc = __shfl_xor(bcol, mask, 64);
                if (ov > best || (ov == best && oc < bcol)) { best = ov; bcol = oc; }
            }
            sw[i] = ssum; bv[i] = best; bc[i] = bcol;
        }
        if (lane < 4) {
            e_lds[base +  64 + w * 4 + lane] = sw[lane];
            e_lds[base + 128 + w * 4 + lane] = bv[lane];
            e_lds[base + 192 + w * 4 + lane] = __int_as_float(bc[lane]);
        }
        __syncthreads();
#pragma unroll
        for (int i = 0; i < 4; ++i) {
            int r = g * 4 + i;
            float so = e_lds[base +  64 + pw * 4 + i];
            float ov = e_lds[base + 128 + pw * 4 + i];
            int   oc = __float_as_int(e_lds[base + 192 + pw * 4 + i]);
            // consistent order: s_half0 + s_half1 on both sides
            float stot = (half == 0) ? __fadd_rn(sw[i], so) : __fadd_rn(so, sw[i]);
            if (ov > bv[i] || (ov == bv[i] && oc < bc[i])) { bv[i] = ov; bc[i] = oc; }
            float invS = 1.0f / stot;
#pragma unroll
            for (int c = 0; c < NCHUNK; ++c)
#pragma unroll
                for (int q = 0; q < 2; ++q)
                    likpart[c][q] = fmaf(acc[c][r][q], invS, likpart[c][q]);
            if (half == 0) {
                int row = rowbase + r;
                __builtin_nontemporal_store(embedT[bc[i] * DIMS + lane],
                                            &out[(size_t)row * DIMS + lane]);
            }
        }
    }

    // ---- block-level likelihood reduction (reuse e_lds[0..511]) ----
    __syncthreads();
    if (tid < KCODES) e_lds[tid] = 0.0f;
    __syncthreads();
#pragma unroll
    for (int c = 0; c < NCHUNK; ++c) {
        atomicAdd(&e_lds[c * CHUNK + colb + 0], likpart[c][0]);
        atomicAdd(&e_lds[c * CHUNK + colb + 1], likpart[c][1]);
    }
    __syncthreads();
    if (tid < KCODES) atomicAdd(&lik[tid], e_lds[tid]);
}

// ---------------------------------------------------------------------------
// finish: likelihoods = lik_sum / N; quant_loss = 0.25*mean(p*(log p - log(l+eps)))
// ---------------------------------------------------------------------------
__global__ void finish_kernel(const float* __restrict__ lik,
                              float* __restrict__ out) {
    int tid = threadIdx.x;   // 512 threads
    float l = lik[tid] / 262144.0f;     // exact: divide by 2^18
    out[16777217 + tid] = l;
    const float p = 1.0f / 512.0f;
    float term = __fmul_rn(p, __fsub_rn(logf(p), logf(l + 1e-10f)));
#pragma unroll
    for (int mask = 1; mask < 64; mask <<= 1)
        term += __shfl_xor(term, mask, 64);
    __shared__ float ws[8];
    if ((tid & 63) == 0) ws[tid >> 6] = term;
    __syncthreads();
    if (tid == 0) {
        float ssum = 0.0f;
        for (int i = 0; i < 8; ++i) ssum += ws[i];
        out[16777216] = 0.25f * (ssum / 512.0f);
    }
}

extern "C" void kernel_launch(void* const* d_in, const int* in_sizes, int n_in,
                              void* d_out, int out_size, void* d_ws, size_t ws_size,
                              hipStream_t stream) {
    const float* x     = (const float*)d_in[0];
    const float* embed = (const float*)d_in[1];
    const float* sigma = (const float*)d_in[2];
    float* out = (float*)d_out;
    float* ws  = (float*)d_ws;

    float* embedT = ws;             // 512*64 = 32768 floats
    float* enorm  = ws + 32768;     // 512 floats
    float* lik    = ws + 33280;     // 512 floats

    prep_kernel<<<KCODES, DIMS, 0, stream>>>(embed, embedT, enorm, lik);
    main_kernel<<<NROWS / MTILE, NTHREADS, 0, stream>>>(x, embed, sigma,
                                                        embedT, enorm, lik, out);
    finish_kernel<<<1, NTHREADS, 0, stream>>>(lik, out);
}

// Round 5
// 801.000 us; speedup vs baseline: 1.1076x; 1.1076x over previous
//
#include <hip/hip_runtime.h>

#define NROWS    262144   // 16 * 16384
#define DIMS     64
#define KCODES   512
#define MTILE    64       // rows per tile
#define NTHREADS 1024     // 16 waves: 8 row-groups x 2 col-halves
#define NBLOCKS  256      // persistent: 1 block/CU
#define NTILES   16       // row-tiles per block (256*16*64 = 262144 rows)

// Dynamic LDS layout (floats): [0,512) exchange/reduce scratch, [512, 512+32768) embed[64][512]
#define LDS_BYTES ((512 + DIMS * KCODES) * 4)

// ---------------------------------------------------------------------------
// prep: embedT[k][d] = embed[d][k]; enorm[k] = sum_d embed[d][k]^2 (numpy
// pairwise-8 order); zero the likelihood accumulator.
// ---------------------------------------------------------------------------
__global__ void prep_kernel(const float* __restrict__ embed,
                            float* __restrict__ embedT,
                            float* __restrict__ enorm,
                            float* __restrict__ lik) {
    int k = blockIdx.x;
    int d = threadIdx.x;
    float v = embed[d * KCODES + k];
    embedT[k * DIMS + d] = v;
    float sq = __fmul_rn(v, v);
    int j = d & 7;
    float r = __shfl(sq, j, 64);
#pragma unroll
    for (int i = 1; i < 8; ++i)
        r = __fadd_rn(r, __shfl(sq, j + 8 * i, 64));
    float t;
    t = __shfl_xor(r, 1, 64); r = __fadd_rn(r, t);
    t = __shfl_xor(r, 2, 64); r = __fadd_rn(r, t);
    t = __shfl_xor(r, 4, 64); r = __fadd_rn(r, t);
    if (d == 0) { enorm[k] = r; lik[k] = 0.0f; }
}

// ---------------------------------------------------------------------------
// main (persistent): 256 blocks x 1024 thr; each block processes 16 row-tiles
// of 64 rows. ALL of embed (128 KB) staged in LDS once -> no chunk loop, no
// mid-GEMM barriers. Wave w: rgrp=w&7 (8 rows), half=w>>3 (256 cols); lane
// owns 4 consecutive cols -> acc[8][4] = 32 VGPRs (fits the allocator's
// 64-VGPR budget; round-1/3 designs with acc=64 spilled 288 MiB).
// x rows are wave-uniform: row base passed through readfirstlane so the
// compiler can use scalar loads (SGPR operands), keeping the vector pipes
// free — round 4's latency stall was dependent per-row global broadcasts.
// Per-element FMA chain / z assembly / argmax tie-break identical to the
// passing round-4 kernel (bit-exact argmax -> absmax 0).
// ---------------------------------------------------------------------------
__global__ void __launch_bounds__(NTHREADS)
main_kernel(const float* __restrict__ x,
            const float* __restrict__ embed,
            const float* __restrict__ sigma,
            const float* __restrict__ embedT,
            const float* __restrict__ enorm,
            float* __restrict__ lik,
            float* __restrict__ out) {
    extern __shared__ float lds[];
    float* scratch = lds;                                   // 512 floats
    float4* eL4 = reinterpret_cast<float4*>(lds + 512);     // embed[64][128 f4]

    const int tid  = threadIdx.x;
    const int lane = tid & 63;
    const int w    = tid >> 6;       // 0..15
    const int rgrp = w & 7;          // row group (8 rows)
    const int half = w >> 3;         // col half 0/1
    const int colb = half * 256 + lane * 4;   // 4 consecutive cols
    const int cb4  = half * 64 + lane;        // float4 index within a d-row
    const int pw   = w ^ 8;                   // pair partner wave

    const float sigma_v = sigma[0];

    const float4* __restrict__ x4  = reinterpret_cast<const float4*>(x);
    const float4* __restrict__ eg4 = reinterpret_cast<const float4*>(embed);

    // ---- stage ALL of embed into LDS (once) ----
#pragma unroll
    for (int i = 0; i < 8; ++i) {
        int idx = tid + i * NTHREADS;          // 0..8191
        eL4[idx] = eg4[idx];
    }
    __syncthreads();

    // enorm for this thread's 4 cols (kernel-lifetime)
    float en[4];
#pragma unroll
    for (int q = 0; q < 4; ++q) en[q] = enorm[colb + q];

    float likpart[4] = {0.0f, 0.0f, 0.0f, 0.0f};

#pragma unroll 1
    for (int t = 0; t < NTILES; ++t) {
        const int rowtile = blockIdx.x * NTILES + t;
        const int rowbase = rowtile * MTILE + rgrp * 8;
        // wave-uniform f4 offset of this wave's first row -> scalar-load path
        const int xof4 = __builtin_amdgcn_readfirstlane(rowbase * 16);

        float acc[8][4];
#pragma unroll
        for (int r = 0; r < 8; ++r)
#pragma unroll
            for (int q = 0; q < 4; ++q) acc[r][q] = 0.0f;

        // ---- GEMM: 16 d4-steps, 128 FMA per step ----
#pragma unroll 1
        for (int d4 = 0; d4 < 16; ++d4) {
            float4 e0 = eL4[(4 * d4 + 0) * 128 + cb4];
            float4 e1 = eL4[(4 * d4 + 1) * 128 + cb4];
            float4 e2 = eL4[(4 * d4 + 2) * 128 + cb4];
            float4 e3 = eL4[(4 * d4 + 3) * 128 + cb4];
#pragma unroll
            for (int r = 0; r < 8; ++r) {
                float4 xv = x4[xof4 + r * 16 + d4];   // uniform addr -> s_load
                acc[r][0] = fmaf(xv.x, e0.x, acc[r][0]);
                acc[r][1] = fmaf(xv.x, e0.y, acc[r][1]);
                acc[r][2] = fmaf(xv.x, e0.z, acc[r][2]);
                acc[r][3] = fmaf(xv.x, e0.w, acc[r][3]);
                acc[r][0] = fmaf(xv.y, e1.x, acc[r][0]);
                acc[r][1] = fmaf(xv.y, e1.y, acc[r][1]);
                acc[r][2] = fmaf(xv.y, e1.z, acc[r][2]);
                acc[r][3] = fmaf(xv.y, e1.w, acc[r][3]);
                acc[r][0] = fmaf(xv.z, e2.x, acc[r][0]);
                acc[r][1] = fmaf(xv.z, e2.y, acc[r][1]);
                acc[r][2] = fmaf(xv.z, e2.z, acc[r][2]);
                acc[r][3] = fmaf(xv.z, e2.w, acc[r][3]);
                acc[r][0] = fmaf(xv.w, e3.x, acc[r][0]);
                acc[r][1] = fmaf(xv.w, e3.y, acc[r][1]);
                acc[r][2] = fmaf(xv.w, e3.z, acc[r][2]);
                acc[r][3] = fmaf(xv.w, e3.w, acc[r][3]);
            }
        }

        // ---- xnorm for the wave's 8 rows (numpy pairwise-8 order) ----
        const int r_l = lane >> 3;
        const int j_l = lane & 7;
        float xr;
        {
            const float* xp = x + (size_t)(rowbase + r_l) * DIMS + j_l;
            float v0 = xp[0];
            float s = __fmul_rn(v0, v0);
#pragma unroll
            for (int i = 1; i < 8; ++i) {
                float v = xp[8 * i];
                s = __fadd_rn(s, __fmul_rn(v, v));
            }
            float tt;
            tt = __shfl_xor(s, 1, 64); s = __fadd_rn(s, tt);
            tt = __shfl_xor(s, 2, 64); s = __fadd_rn(s, tt);
            tt = __shfl_xor(s, 4, 64); s = __fadd_rn(s, tt);
            xr = s;   // lane r*8+j holds xnorm of row r
        }

        // ---- softmax/argmax epilogue, 2 groups of 4 rows ----
#pragma unroll 1
        for (int g = 0; g < 2; ++g) {
            const int base = g * 256;
            float mw4[4];
#pragma unroll
            for (int i = 0; i < 4; ++i) {
                int r = g * 4 + i;
                float xn = __shfl(xr, r * 8, 64);
                float mm = -INFINITY;
#pragma unroll
                for (int q = 0; q < 4; ++q) {
                    float dot  = acc[r][q];
                    float td   = __fsub_rn(xn, __fmul_rn(2.0f, dot));
                    float dist = __fadd_rn(td, en[q]);
                    float zz   = __fmul_rn(-sigma_v, dist);
                    acc[r][q] = zz;
                    mm = fmaxf(mm, zz);
                }
#pragma unroll
                for (int mask = 1; mask < 64; mask <<= 1)
                    mm = fmaxf(mm, __shfl_xor(mm, mask, 64));
                mw4[i] = mm;
            }
            if (lane < 4) scratch[base + w * 4 + lane] = mw4[lane];
            __syncthreads();
#pragma unroll
            for (int i = 0; i < 4; ++i)
                mw4[i] = fmaxf(mw4[i], scratch[base + pw * 4 + i]);

            float sw[4], bv[4]; int bc[4];
#pragma unroll
            for (int i = 0; i < 4; ++i) {
                int r = g * 4 + i;
                float ssum = 0.0f, best = -1.0f; int bcol = KCODES;
#pragma unroll
                for (int q = 0; q < 4; ++q) {
                    float ee = expf(__fsub_rn(acc[r][q], mw4[i]));
                    acc[r][q] = ee;
                    ssum += ee;
                    int col = colb + q;
                    if (ee > best) { best = ee; bcol = col; }
                }
#pragma unroll
                for (int mask = 1; mask < 64; mask <<= 1)
                    ssum += __shfl_xor(ssum, mask, 64);
#pragma unroll
                for (int mask = 1; mask < 64; mask <<= 1) {
                    float ov = __shfl_xor(best, mask, 64);
                    int   oc = __shfl_xor(bcol, mask, 64);
                    if (ov > best || (ov == best && oc < bcol)) { best = ov; bcol = oc; }
                }
                sw[i] = ssum; bv[i] = best; bc[i] = bcol;
            }
            if (lane < 4) {
                scratch[base +  64 + w * 4 + lane] = sw[lane];
                scratch[base + 128 + w * 4 + lane] = bv[lane];
                scratch[base + 192 + w * 4 + lane] = __int_as_float(bc[lane]);
            }
            __syncthreads();
#pragma unroll
            for (int i = 0; i < 4; ++i) {
                int r = g * 4 + i;
                float so = scratch[base +  64 + pw * 4 + i];
                float ov = scratch[base + 128 + pw * 4 + i];
                int   oc = __float_as_int(scratch[base + 192 + pw * 4 + i]);
                float stot = (half == 0) ? __fadd_rn(sw[i], so) : __fadd_rn(so, sw[i]);
                if (ov > bv[i] || (ov == bv[i] && oc < bc[i])) { bv[i] = ov; bc[i] = oc; }
                float invS = 1.0f / stot;
#pragma unroll
                for (int q = 0; q < 4; ++q)
                    likpart[q] = fmaf(acc[r][q], invS, likpart[q]);
                if (half == 0) {
                    int row = rowbase + r;
                    __builtin_nontemporal_store(embedT[bc[i] * DIMS + lane],
                                                &out[(size_t)row * DIMS + lane]);
                }
            }
        }
        __syncthreads();   // protect scratch WAR before next tile
    }

    // ---- block-level likelihood reduction (scratch[0..511]) ----
    if (tid < KCODES) scratch[tid] = 0.0f;
    __syncthreads();
#pragma unroll
    for (int q = 0; q < 4; ++q)
        atomicAdd(&scratch[colb + q], likpart[q]);
    __syncthreads();
    if (tid < KCODES) atomicAdd(&lik[tid], scratch[tid]);
}

// ---------------------------------------------------------------------------
// finish: likelihoods = lik_sum / N; quant_loss = 0.25*mean(p*(log p - log(l+eps)))
// ---------------------------------------------------------------------------
__global__ void finish_kernel(const float* __restrict__ lik,
                              float* __restrict__ out) {
    int tid = threadIdx.x;   // 512 threads
    float l = lik[tid] / 262144.0f;     // exact: divide by 2^18
    out[16777217 + tid] = l;
    const float p = 1.0f / 512.0f;
    float term = __fmul_rn(p, __fsub_rn(logf(p), logf(l + 1e-10f)));
#pragma unroll
    for (int mask = 1; mask < 64; mask <<= 1)
        term += __shfl_xor(term, mask, 64);
    __shared__ float ws[8];
    if ((tid & 63) == 0) ws[tid >> 6] = term;
    __syncthreads();
    if (tid == 0) {
        float ssum = 0.0f;
        for (int i = 0; i < 8; ++i) ssum += ws[i];
        out[16777216] = 0.25f * (ssum / 512.0f);
    }
}

extern "C" void kernel_launch(void* const* d_in, const int* in_sizes, int n_in,
                              void* d_out, int out_size, void* d_ws, size_t ws_size,
                              hipStream_t stream) {
    const float* x     = (const float*)d_in[0];
    const float* embed = (const float*)d_in[1];
    const float* sigma = (const float*)d_in[2];
    float* out = (float*)d_out;
    float* ws  = (float*)d_ws;

    float* embedT = ws;             // 512*64 = 32768 floats
    float* enorm  = ws + 32768;     // 512 floats
    float* lik    = ws + 33280;     // 512 floats

    // allow 130 KB dynamic LDS (MI355X: 160 KB/CU)
    static int attr_done = 0;
    (void)attr_done;
    hipFuncSetAttribute(reinterpret_cast<const void*>(main_kernel),
                        hipFuncAttributeMaxDynamicSharedMemorySize, LDS_BYTES);

    prep_kernel<<<KCODES, DIMS, 0, stream>>>(embed, embedT, enorm, lik);
    main_kernel<<<NBLOCKS, NTHREADS, LDS_BYTES, stream>>>(x, embed, sigma,
                                                          embedT, enorm, lik, out);
    finish_kernel<<<1, NTHREADS, 0, stream>>>(lik, out);
}

// Round 6
// 779.733 us; speedup vs baseline: 1.1378x; 1.0273x over previous
//
#include <hip/hip_runtime.h>

#define NROWS    262144   // 16 * 16384
#define DIMS     64
#define KCODES   512
#define MTILE    64       // rows per tile
#define NTHREADS 1024     // 16 waves: 8 row-groups x 2 col-halves
#define NBLOCKS  256      // persistent: 1 block/CU
#define NTILES   16       // row-tiles per block (256*16*64 = 262144 rows)

// Dynamic LDS layout (floats):
//   [0,512)      exchange/reduce scratch
//   [512,1024)   enorm staged copy
//   [1024,+32768) embed[64][512]
#define LDS_FLOATS (1024 + DIMS * KCODES)
#define LDS_BYTES  (LDS_FLOATS * 4)

// ---------------------------------------------------------------------------
// prep: embedT[k][d] = embed[d][k]; enorm[k] = sum_d embed[d][k]^2 (numpy
// pairwise-8 order); zero the likelihood accumulator.
// ---------------------------------------------------------------------------
__global__ void prep_kernel(const float* __restrict__ embed,
                            float* __restrict__ embedT,
                            float* __restrict__ enorm,
                            float* __restrict__ lik) {
    int k = blockIdx.x;
    int d = threadIdx.x;
    float v = embed[d * KCODES + k];
    embedT[k * DIMS + d] = v;
    float sq = __fmul_rn(v, v);
    int j = d & 7;
    float r = __shfl(sq, j, 64);
#pragma unroll
    for (int i = 1; i < 8; ++i)
        r = __fadd_rn(r, __shfl(sq, j + 8 * i, 64));
    float t;
    t = __shfl_xor(r, 1, 64); r = __fadd_rn(r, t);
    t = __shfl_xor(r, 2, 64); r = __fadd_rn(r, t);
    t = __shfl_xor(r, 4, 64); r = __fadd_rn(r, t);
    if (d == 0) { enorm[k] = r; lik[k] = 0.0f; }
}

// ---------------------------------------------------------------------------
// main (persistent): 256 blocks x 1024 thr; block processes 16 row-tiles of
// 64 rows. Full embed (128 KB) staged in LDS once. Wave w: rgrp=w&7 (8 rows),
// half=w>>3 (256 cols); lane owns 4 consecutive cols -> acc[8][4] = 32 VGPRs.
//
// OCCUPANCY PIN (the round-1..5 saga): the backend sets its VGPR budget from
// an occupancy guess. With dynamic LDS it guessed ~11 waves/EU -> 44-VGPR
// budget -> 1.6 GB of per-tile scratch spill traffic (round 5). Real
// occupancy is LDS-capped at 1 block/CU = 4 waves/EU. amdgpu_waves_per_eu(4,4)
// (native attr, no __launch_bounds__ to conflict with) pins the guess and
// legalizes a 128-VGPR budget. enorm is additionally staged in LDS so the
// GEMM-phase live set (~56) fits even a stubborn 64-VGPR budget.
// Numerics identical to rounds 4/5 (absmax 0).
// ---------------------------------------------------------------------------
__global__ void
__attribute__((amdgpu_flat_work_group_size(1024, 1024), amdgpu_waves_per_eu(4, 4)))
main_kernel(const float* __restrict__ x,
            const float* __restrict__ embed,
            const float* __restrict__ sigma,
            const float* __restrict__ embedT,
            const float* __restrict__ enorm,
            float* __restrict__ lik,
            float* __restrict__ out) {
    extern __shared__ float lds[];
    float* scratch = lds;                                    // 512 floats
    float* enL     = lds + 512;                              // 512 floats
    float4* eL4 = reinterpret_cast<float4*>(lds + 1024);     // embed[64][128 f4]

    const int tid  = threadIdx.x;
    const int lane = tid & 63;
    const int w    = tid >> 6;       // 0..15
    const int rgrp = w & 7;          // row group (8 rows)
    const int half = w >> 3;         // col half 0/1
    const int colb = half * 256 + lane * 4;   // 4 consecutive cols
    const int cb4  = half * 64 + lane;        // float4 index within a d-row
    const int pw   = w ^ 8;                   // pair partner wave

    const float sigma_v = sigma[0];

    const float4* __restrict__ x4  = reinterpret_cast<const float4*>(x);
    const float4* __restrict__ eg4 = reinterpret_cast<const float4*>(embed);

    // ---- stage embed + enorm into LDS (once) ----
#pragma unroll
    for (int i = 0; i < 8; ++i) {
        int idx = tid + i * NTHREADS;          // 0..8191
        eL4[idx] = eg4[idx];
    }
    if (tid < KCODES) enL[tid] = enorm[tid];
    __syncthreads();

    float likpart[4] = {0.0f, 0.0f, 0.0f, 0.0f};

#pragma unroll 1
    for (int t = 0; t < NTILES; ++t) {
        const int rowtile = blockIdx.x * NTILES + t;
        const int rowbase = rowtile * MTILE + rgrp * 8;
        // wave-uniform f4 offset of this wave's first row -> scalar addressing
        const int xof4 = __builtin_amdgcn_readfirstlane(rowbase * 16);

        float acc[8][4];
#pragma unroll
        for (int r = 0; r < 8; ++r)
#pragma unroll
            for (int q = 0; q < 4; ++q) acc[r][q] = 0.0f;

        // ---- GEMM: 16 d4-steps, 128 FMA per step ----
#pragma unroll 1
        for (int d4 = 0; d4 < 16; ++d4) {
            float4 e0 = eL4[(4 * d4 + 0) * 128 + cb4];
            float4 e1 = eL4[(4 * d4 + 1) * 128 + cb4];
            float4 e2 = eL4[(4 * d4 + 2) * 128 + cb4];
            float4 e3 = eL4[(4 * d4 + 3) * 128 + cb4];
#pragma unroll
            for (int r = 0; r < 8; ++r) {
                float4 xv = x4[xof4 + r * 16 + d4];   // wave-uniform address
                acc[r][0] = fmaf(xv.x, e0.x, acc[r][0]);
                acc[r][1] = fmaf(xv.x, e0.y, acc[r][1]);
                acc[r][2] = fmaf(xv.x, e0.z, acc[r][2]);
                acc[r][3] = fmaf(xv.x, e0.w, acc[r][3]);
                acc[r][0] = fmaf(xv.y, e1.x, acc[r][0]);
                acc[r][1] = fmaf(xv.y, e1.y, acc[r][1]);
                acc[r][2] = fmaf(xv.y, e1.z, acc[r][2]);
                acc[r][3] = fmaf(xv.y, e1.w, acc[r][3]);
                acc[r][0] = fmaf(xv.z, e2.x, acc[r][0]);
                acc[r][1] = fmaf(xv.z, e2.y, acc[r][1]);
                acc[r][2] = fmaf(xv.z, e2.z, acc[r][2]);
                acc[r][3] = fmaf(xv.z, e2.w, acc[r][3]);
                acc[r][0] = fmaf(xv.w, e3.x, acc[r][0]);
                acc[r][1] = fmaf(xv.w, e3.y, acc[r][1]);
                acc[r][2] = fmaf(xv.w, e3.z, acc[r][2]);
                acc[r][3] = fmaf(xv.w, e3.w, acc[r][3]);
            }
        }

        // ---- xnorm for the wave's 8 rows (numpy pairwise-8 order) ----
        const int r_l = lane >> 3;
        const int j_l = lane & 7;
        float xr;
        {
            const float* xp = x + (size_t)(rowbase + r_l) * DIMS + j_l;
            float v0 = xp[0];
            float s = __fmul_rn(v0, v0);
#pragma unroll
            for (int i = 1; i < 8; ++i) {
                float v = xp[8 * i];
                s = __fadd_rn(s, __fmul_rn(v, v));
            }
            float tt;
            tt = __shfl_xor(s, 1, 64); s = __fadd_rn(s, tt);
            tt = __shfl_xor(s, 2, 64); s = __fadd_rn(s, tt);
            tt = __shfl_xor(s, 4, 64); s = __fadd_rn(s, tt);
            xr = s;   // lane r*8+j holds xnorm of row r
        }

        // enorm for this thread's 4 cols (transient, from LDS)
        float4 env = reinterpret_cast<const float4*>(enL)[cb4];
        float en[4] = {env.x, env.y, env.z, env.w};

        // ---- softmax/argmax epilogue, 2 groups of 4 rows ----
#pragma unroll 1
        for (int g = 0; g < 2; ++g) {
            const int base = g * 256;
            float mw4[4];
#pragma unroll
            for (int i = 0; i < 4; ++i) {
                int r = g * 4 + i;
                float xn = __shfl(xr, r * 8, 64);
                float mm = -INFINITY;
#pragma unroll
                for (int q = 0; q < 4; ++q) {
                    float dot  = acc[r][q];
                    float td   = __fsub_rn(xn, __fmul_rn(2.0f, dot));
                    float dist = __fadd_rn(td, en[q]);
                    float zz   = __fmul_rn(-sigma_v, dist);
                    acc[r][q] = zz;
                    mm = fmaxf(mm, zz);
                }
#pragma unroll
                for (int mask = 1; mask < 64; mask <<= 1)
                    mm = fmaxf(mm, __shfl_xor(mm, mask, 64));
                mw4[i] = mm;
            }
            if (lane < 4) scratch[base + w * 4 + lane] = mw4[lane];
            __syncthreads();
#pragma unroll
            for (int i = 0; i < 4; ++i)
                mw4[i] = fmaxf(mw4[i], scratch[base + pw * 4 + i]);

            float sw[4], bv[4]; int bc[4];
#pragma unroll
            for (int i = 0; i < 4; ++i) {
                int r = g * 4 + i;
                float ssum = 0.0f, best = -1.0f; int bcol = KCODES;
#pragma unroll
                for (int q = 0; q < 4; ++q) {
                    float ee = expf(__fsub_rn(acc[r][q], mw4[i]));
                    acc[r][q] = ee;
                    ssum += ee;
                    int col = colb + q;
                    if (ee > best) { best = ee; bcol = col; }
                }
#pragma unroll
                for (int mask = 1; mask < 64; mask <<= 1)
                    ssum += __shfl_xor(ssum, mask, 64);
#pragma unroll
                for (int mask = 1; mask < 64; mask <<= 1) {
                    float ov = __shfl_xor(best, mask, 64);
                    int   oc = __shfl_xor(bcol, mask, 64);
                    if (ov > best || (ov == best && oc < bcol)) { best = ov; bcol = oc; }
                }
                sw[i] = ssum; bv[i] = best; bc[i] = bcol;
            }
            if (lane < 4) {
                scratch[base +  64 + w * 4 + lane] = sw[lane];
                scratch[base + 128 + w * 4 + lane] = bv[lane];
                scratch[base + 192 + w * 4 + lane] = __int_as_float(bc[lane]);
            }
            __syncthreads();
#pragma unroll
            for (int i = 0; i < 4; ++i) {
                int r = g * 4 + i;
                float so = scratch[base +  64 + pw * 4 + i];
                float ov = scratch[base + 128 + pw * 4 + i];
                int   oc = __float_as_int(scratch[base + 192 + pw * 4 + i]);
                float stot = (half == 0) ? __fadd_rn(sw[i], so) : __fadd_rn(so, sw[i]);
                if (ov > bv[i] || (ov == bv[i] && oc < bc[i])) { bv[i] = ov; bc[i] = oc; }
                float invS = 1.0f / stot;
#pragma unroll
                for (int q = 0; q < 4; ++q)
                    likpart[q] = fmaf(acc[r][q], invS, likpart[q]);
                if (half == 0) {
                    int row = rowbase + r;
                    __builtin_nontemporal_store(embedT[bc[i] * DIMS + lane],
                                                &out[(size_t)row * DIMS + lane]);
                }
            }
        }
        __syncthreads();   // protect scratch WAR before next tile
    }

    // ---- block-level likelihood reduction (scratch[0..511]) ----
    if (tid < KCODES) scratch[tid] = 0.0f;
    __syncthreads();
#pragma unroll
    for (int q = 0; q < 4; ++q)
        atomicAdd(&scratch[colb + q], likpart[q]);
    __syncthreads();
    if (tid < KCODES) atomicAdd(&lik[tid], scratch[tid]);
}

// ---------------------------------------------------------------------------
// finish: likelihoods = lik_sum / N; quant_loss = 0.25*mean(p*(log p - log(l+eps)))
// ---------------------------------------------------------------------------
__global__ void finish_kernel(const float* __restrict__ lik,
                              float* __restrict__ out) {
    int tid = threadIdx.x;   // 512 threads
    float l = lik[tid] / 262144.0f;     // exact: divide by 2^18
    out[16777217 + tid] = l;
    const float p = 1.0f / 512.0f;
    float term = __fmul_rn(p, __fsub_rn(logf(p), logf(l + 1e-10f)));
#pragma unroll
    for (int mask = 1; mask < 64; mask <<= 1)
        term += __shfl_xor(term, mask, 64);
    __shared__ float ws[8];
    if ((tid & 63) == 0) ws[tid >> 6] = term;
    __syncthreads();
    if (tid == 0) {
        float ssum = 0.0f;
        for (int i = 0; i < 8; ++i) ssum += ws[i];
        out[16777216] = 0.25f * (ssum / 512.0f);
    }
}

extern "C" void kernel_launch(void* const* d_in, const int* in_sizes, int n_in,
                              void* d_out, int out_size, void* d_ws, size_t ws_size,
                              hipStream_t stream) {
    const float* x     = (const float*)d_in[0];
    const float* embed = (const float*)d_in[1];
    const float* sigma = (const float*)d_in[2];
    float* out = (float*)d_out;
    float* ws  = (float*)d_ws;

    float* embedT = ws;             // 512*64 = 32768 floats
    float* enorm  = ws + 32768;     // 512 floats
    float* lik    = ws + 33280;     // 512 floats

    hipFuncSetAttribute(reinterpret_cast<const void*>(main_kernel),
                        hipFuncAttributeMaxDynamicSharedMemorySize, LDS_BYTES);

    prep_kernel<<<KCODES, DIMS, 0, stream>>>(embed, embedT, enorm, lik);
    main_kernel<<<NBLOCKS, NTHREADS, LDS_BYTES, stream>>>(x, embed, sigma,
                                                          embedT, enorm, lik, out);
    finish_kernel<<<1, NTHREADS, 0, stream>>>(lik, out);
}